// Round 3
// baseline (679.570 us; speedup 1.0000x reference)
//
#include <hip/hip_runtime.h>
#include <hip/hip_bf16.h>

#define B_ 64
#define S_ 2048
#define D_ 512   // D_ENC = D_DEC = UNITS = 512

typedef __attribute__((ext_vector_type(8))) short bf16x8;
typedef __attribute__((ext_vector_type(4))) float f32x4;

__device__ inline short f2bf(float f) {
    __hip_bfloat16 h = __float2bfloat16(f);   // RNE
    return __builtin_bit_cast(short, h);
}
__device__ inline float bf2f(short s) {
    return __uint_as_float(((unsigned)(unsigned short)s) << 16);
}
__device__ inline float fast_tanh(float x) {
    float xc = fminf(fmaxf(x, -15.f), 15.f);
    float t = __expf(2.f * xc);
    return (t - 1.f) * __builtin_amdgcn_rcpf(t + 1.f);
}

// ---------------- kernel 0: hdec[b][u] = dec[b]@W2[:,u] + b1[u] + b2[u] ----------------
__global__ void hdec_kernel(const float* __restrict__ dec, const float* __restrict__ W2,
                            const float* __restrict__ b1, const float* __restrict__ b2,
                            float* __restrict__ hdec)
{
    int b = blockIdx.x;          // 64
    int u = threadIdx.x;         // 512
    float acc = b1[u] + b2[u];
    const float* db = dec + b * 512;
    #pragma unroll 8
    for (int k = 0; k < 512; ++k)
        acc = fmaf(db[k], W2[(size_t)k * 512 + u], acc);
    hdec[b * 512 + u] = acc;
}

// ---------------- kernel 0b: W1T[u][d] = bf16(W1[d][u]) ----------------
__global__ void w1t_kernel(const float* __restrict__ W1, short* __restrict__ W1T)
{
    __shared__ float tile[64][65];
    int d0 = blockIdx.x * 64;
    int u0 = blockIdx.y * 64;
    int tx = threadIdx.x & 63;
    int ty = threadIdx.x >> 6;   // 0..3
    #pragma unroll
    for (int i = 0; i < 16; ++i) {
        int d = ty + i * 4;
        tile[d][tx] = W1[(size_t)(d0 + d) * 512 + u0 + tx];
    }
    __syncthreads();
    #pragma unroll
    for (int i = 0; i < 16; ++i) {
        int u = ty + i * 4;
        W1T[(size_t)(u0 + u) * 512 + d0 + tx] = f2bf(tile[tx][u]);
    }
}

// ---------------- main fused kernel ----------------
// grid 1024 = 64 b x 16 chunks of 128 rows; block 256 (4 waves, 32 rows/wave)
__global__ __launch_bounds__(256, 2)
void attn_main(const float* __restrict__ enc, const short* __restrict__ W1T,
               const float* __restrict__ hdec, const float* __restrict__ Vv,
               float* __restrict__ partials)
{
    const int blk = blockIdx.x;
    const int b = blk >> 4;
    const int chunk = blk & 15;
    const int s0 = chunk * 128;
    const int tid = threadIdx.x;
    const int w = tid >> 6;
    const int l = tid & 63;
    const int lc = l & 15;    // mfma row/col within tile
    const int lg = l >> 4;    // k-group

    const float* encB = enc + ((size_t)b * S_ + s0) * D_;

    // ---- load A fragments (enc rows, bf16), keep resident for ctx reuse ----
    // A layout (16x16x32): lane holds A[row=lc][k=lg*8+j]; row-groups g cover rows w*32+g*16+lc
    bf16x8 a[2][16];
    #pragma unroll
    for (int g = 0; g < 2; ++g) {
        const float* rp = encB + (size_t)(w * 32 + g * 16 + lc) * D_ + lg * 8;
        #pragma unroll
        for (int kk = 0; kk < 16; ++kk) {
            f32x4 p0 = *(const f32x4*)(rp + kk * 32);
            f32x4 p1 = *(const f32x4*)(rp + kk * 32 + 4);
            bf16x8 af;
            af[0] = f2bf(p0[0]); af[1] = f2bf(p0[1]); af[2] = f2bf(p0[2]); af[3] = f2bf(p0[3]);
            af[4] = f2bf(p1[0]); af[5] = f2bf(p1[1]); af[6] = f2bf(p1[2]); af[7] = f2bf(p1[3]);
            a[g][kk] = af;
        }
    }

    // ---- score GEMM: loop 32 u-tiles of 16, K=512 ----
    float sacc[2][4] = {{0.f,0.f,0.f,0.f},{0.f,0.f,0.f,0.f}};
    for (int n = 0; n < 32; ++n) {
        const short* bp = W1T + (size_t)(n * 16 + lc) * D_ + lg * 8;
        bf16x8 bfr[16];
        #pragma unroll
        for (int kk = 0; kk < 16; ++kk)
            bfr[kk] = *(const bf16x8*)(bp + kk * 32);
        f32x4 acc0 = {0.f,0.f,0.f,0.f}, acc1 = {0.f,0.f,0.f,0.f};
        #pragma unroll
        for (int kk = 0; kk < 16; ++kk) {
            acc0 = __builtin_amdgcn_mfma_f32_16x16x32_bf16(a[0][kk], bfr[kk], acc0, 0, 0, 0);
            acc1 = __builtin_amdgcn_mfma_f32_16x16x32_bf16(a[1][kk], bfr[kk], acc1, 0, 0, 0);
        }
        // D layout: lane holds D[row=lg*4+r][col=lc]; u = n*16+lc
        float hd = hdec[b * 512 + n * 16 + lc];
        float vv = Vv[n * 16 + lc];
        #pragma unroll
        for (int r = 0; r < 4; ++r) {
            sacc[0][r] += fast_tanh(acc0[r] + hd) * vv;
            sacc[1][r] += fast_tanh(acc1[r] + hd) * vv;
        }
    }

    __shared__ float s_sc[128];
    __shared__ float s_p[128];
    __shared__ float s_red[8];
    __shared__ float s_ctx[4][512];

    // ---- reduce scores over the 16 lanes sharing lg (cols), write per-row scores ----
    #pragma unroll
    for (int g = 0; g < 2; ++g) {
        #pragma unroll
        for (int r = 0; r < 4; ++r) {
            float v = sacc[g][r];
            v += __shfl_xor(v, 1);
            v += __shfl_xor(v, 2);
            v += __shfl_xor(v, 4);
            v += __shfl_xor(v, 8);
            if (lc == 0) s_sc[w * 32 + g * 16 + lg * 4 + r] = v;
        }
    }
    __syncthreads();

    // ---- block softmax partial: m, l, p[row] ----
    float x = (tid < 128) ? s_sc[tid] : -1e30f;
    float mx = x;
    #pragma unroll
    for (int o = 32; o >= 1; o >>= 1) mx = fmaxf(mx, __shfl_xor(mx, o));
    if (l == 0) s_red[w] = mx;
    __syncthreads();
    float m_blk = fmaxf(fmaxf(s_red[0], s_red[1]), fmaxf(s_red[2], s_red[3]));
    float p = (tid < 128) ? __expf(x - m_blk) : 0.f;
    if (tid < 128) s_p[tid] = p;
    float ps = p;
    #pragma unroll
    for (int o = 32; o >= 1; o >>= 1) ps += __shfl_xor(ps, o);
    if (l == 0) s_red[4 + w] = ps;
    __syncthreads();
    float l_blk = s_red[4] + s_red[5] + s_red[6] + s_red[7];

    // ---- context partial, reusing A fragments in registers ----
    float w0 = s_p[w * 32 + lc];        // row w*32+0*16+lc
    float w1 = s_p[w * 32 + 16 + lc];   // row w*32+1*16+lc
    #pragma unroll
    for (int kk = 0; kk < 16; ++kk) {
        float v8[8];
        #pragma unroll
        for (int j = 0; j < 8; ++j) {
            float e0 = bf2f(a[0][kk][j]);
            float e1 = bf2f(a[1][kk][j]);
            v8[j] = w0 * e0 + w1 * e1;
        }
        #pragma unroll
        for (int j = 0; j < 8; ++j) {
            v8[j] += __shfl_xor(v8[j], 1);
            v8[j] += __shfl_xor(v8[j], 2);
            v8[j] += __shfl_xor(v8[j], 4);
            v8[j] += __shfl_xor(v8[j], 8);
        }
        if (lc == 0) {
            #pragma unroll
            for (int j = 0; j < 8; ++j)
                s_ctx[w][kk * 32 + lg * 8 + j] = v8[j];   // d = kk*32 + lg*8 + j
        }
    }
    __syncthreads();

    // ---- combine waves, write partial record (ctx[512], m, l) ----
    float* part = partials + (size_t)blk * 514;
    for (int d = tid; d < 512; d += 256)
        part[d] = s_ctx[0][d] + s_ctx[1][d] + s_ctx[2][d] + s_ctx[3][d];
    if (tid == 0) { part[512] = m_blk; part[513] = l_blk; }
}

// ---------------- merge kernel: online-softmax merge of 16 chunks per batch ----------------
__global__ void merge_kernel(const float* __restrict__ partials, float* __restrict__ out)
{
    int b = blockIdx.x;     // 64
    int tid = threadIdx.x;  // 256
    const float* pb = partials + (size_t)b * 16 * 514;
    float M = -1e30f;
    #pragma unroll
    for (int i = 0; i < 16; ++i) M = fmaxf(M, pb[i * 514 + 512]);
    float sc[16]; float L = 0.f;
    #pragma unroll
    for (int i = 0; i < 16; ++i) {
        sc[i] = __expf(pb[i * 514 + 512] - M);
        L += pb[i * 514 + 513] * sc[i];
    }
    float inv = 1.0f / L;
    for (int d = tid; d < 512; d += 256) {
        float acc = 0.f;
        #pragma unroll
        for (int i = 0; i < 16; ++i) acc += pb[i * 514 + d] * sc[i];
        out[b * 512 + d] = acc * inv;
    }
}

extern "C" void kernel_launch(void* const* d_in, const int* in_sizes, int n_in,
                              void* d_out, int out_size, void* d_ws, size_t ws_size,
                              hipStream_t stream)
{
    const float* enc = (const float*)d_in[0];
    const float* dec = (const float*)d_in[1];
    const float* W1  = (const float*)d_in[2];
    const float* b1  = (const float*)d_in[3];
    const float* W2  = (const float*)d_in[4];
    const float* b2  = (const float*)d_in[5];
    const float* V   = (const float*)d_in[6];
    // d_in[7] = bv: softmax-invariant, dropped.
    float* out = (float*)d_out;

    char* ws = (char*)d_ws;
    float* hdec     = (float*)ws;                                 // 64*512 f32   = 128 KiB
    short* W1T      = (short*)(ws + 64 * 512 * 4);                // 512*512 bf16 = 512 KiB
    float* partials = (float*)(ws + 64 * 512 * 4 + 512 * 512 * 2); // 1024*514 f32 ~ 2 MiB

    hipLaunchKernelGGL(hdec_kernel, dim3(64), dim3(512), 0, stream, dec, W2, b1, b2, hdec);
    hipLaunchKernelGGL(w1t_kernel, dim3(8, 8), dim3(256), 0, stream, W1, W1T);
    hipLaunchKernelGGL(attn_main, dim3(1024), dim3(256), 0, stream, enc, W1T, hdec, V, partials);
    hipLaunchKernelGGL(merge_kernel, dim3(64), dim3(256), 0, stream, partials, out);
}

// Round 4
// 525.063 us; speedup vs baseline: 1.2943x; 1.2943x over previous
//
#include <hip/hip_runtime.h>
#include <hip/hip_bf16.h>

#define B_ 64
#define S_ 2048
#define D_ 512   // D_ENC = D_DEC = UNITS = 512
#define ROWS 64  // enc rows per block

typedef __attribute__((ext_vector_type(8))) short bf16x8;
typedef __attribute__((ext_vector_type(4))) float f32x4;

__device__ inline short f2bf(float f) {
    __hip_bfloat16 h = __float2bfloat16(f);   // RNE
    return __builtin_bit_cast(short, h);
}
__device__ inline float bf2f(short s) {
    return __uint_as_float(((unsigned)(unsigned short)s) << 16);
}
__device__ inline float fast_tanh(float x) {
    float xc = fminf(fmaxf(x, -15.f), 15.f);
    float t = __expf(2.f * xc);
    return (t - 1.f) * __builtin_amdgcn_rcpf(t + 1.f);
}

// ---------------- hdec[b][u] = dec[b]@W2[:,u] + b1[u] + b2[u] ----------------
// 256 blocks x 128 threads: block = (b, u-chunk of 128); dec row staged in LDS.
__global__ __launch_bounds__(128)
void hdec_kernel(const float* __restrict__ dec, const float* __restrict__ W2,
                 const float* __restrict__ b1, const float* __restrict__ b2,
                 float* __restrict__ hdec)
{
    int b = blockIdx.x >> 2;
    int u = (blockIdx.x & 3) * 128 + threadIdx.x;
    __shared__ float ds[512];
    for (int i = threadIdx.x; i < 512; i += 128) ds[i] = dec[b * 512 + i];
    __syncthreads();
    float acc = b1[u] + b2[u];
    const float* wp = W2 + u;
    #pragma unroll 8
    for (int k = 0; k < 512; ++k)
        acc = fmaf(ds[k], wp[(size_t)k * 512], acc);
    hdec[b * 512 + u] = acc;
}

// ---------------- W1T[u][d] = bf16(W1[d][u]) ----------------
__global__ void w1t_kernel(const float* __restrict__ W1, short* __restrict__ W1T)
{
    __shared__ float tile[64][65];
    int d0 = blockIdx.x * 64;
    int u0 = blockIdx.y * 64;
    int tx = threadIdx.x & 63;
    int ty = threadIdx.x >> 6;   // 0..3
    #pragma unroll
    for (int i = 0; i < 16; ++i) {
        int d = ty + i * 4;
        tile[d][tx] = W1[(size_t)(d0 + d) * 512 + u0 + tx];
    }
    __syncthreads();
    #pragma unroll
    for (int i = 0; i < 16; ++i) {
        int u = ty + i * 4;
        W1T[(size_t)(u0 + u) * 512 + d0 + tx] = f2bf(tile[tx][u]);
    }
}

// ---------------- main fused kernel ----------------
// grid 2048 = 64 b x 32 chunks of 64 rows; block 256 (4 waves).
// Waves split the u-dimension: wave w owns u = w*128 .. w*128+127 for ALL 64 rows.
// enc tile staged once in LDS (bf16, XOR-swizzled), reused by score GEMM + context.
__global__ __launch_bounds__(256, 2)
void attn_main(const float* __restrict__ enc, const short* __restrict__ W1T,
               const float* __restrict__ hdec, const float* __restrict__ Vv,
               float* __restrict__ partials)
{
    const int blk = blockIdx.x;
    const int b = blk >> 5;
    const int chunk = blk & 31;
    const int tid = threadIdx.x;
    const int w = tid >> 6;
    const int l = tid & 63;
    const int lc = l & 15;    // mfma row/col within 16x16 tile
    const int lg = l >> 4;    // k-group

    __shared__ short enc_s[ROWS * 512];   // 64 KB, byte ^ ((row&7)<<4) swizzle
    __shared__ float s_sc[4][64];
    __shared__ float s_p[64];
    __shared__ float s_ml[2];
    __shared__ float s_ctx[4][512];

    const float* encB = enc + ((size_t)b * S_ + chunk * ROWS) * D_;

    // ---- P1: stage enc tile -> LDS bf16 (swizzled). Coalesced 32B/thread/iter. ----
    #pragma unroll
    for (int i = 0; i < 16; ++i) {
        int e = i * 2048 + tid * 8;            // elem index in [64][512]
        f32x4 p0 = *(const f32x4*)(encB + e);
        f32x4 p1 = *(const f32x4*)(encB + e + 4);
        bf16x8 v;
        v[0] = f2bf(p0[0]); v[1] = f2bf(p0[1]); v[2] = f2bf(p0[2]); v[3] = f2bf(p0[3]);
        v[4] = f2bf(p1[0]); v[5] = f2bf(p1[1]); v[6] = f2bf(p1[2]); v[7] = f2bf(p1[3]);
        int row = e >> 9;
        int byte = (e * 2) ^ ((row & 7) << 4);
        *(bf16x8*)((char*)enc_s + byte) = v;
    }
    __syncthreads();

    // ---- P2: score GEMM. Wave w: u-tiles n = w*8 .. w*8+7, NU=2 grouping. ----
    float sacc[4][4];   // [rowgroup g][r]: partial sum over this wave's u-range
    #pragma unroll
    for (int g = 0; g < 4; ++g)
        #pragma unroll
        for (int r = 0; r < 4; ++r) sacc[g][r] = 0.f;

    for (int np = 0; np < 4; ++np) {          // pairs of u-tiles
        f32x4 acc[4][2] = {};                 // [g][nn]
        #pragma unroll 4
        for (int kk = 0; kk < 16; ++kk) {
            bf16x8 a[4], bb[2];
            #pragma unroll
            for (int g = 0; g < 4; ++g) {
                int row = g * 16 + lc;
                int byte = (row * 1024 + (kk * 32 + lg * 8) * 2) ^ ((lc & 7) << 4);
                a[g] = *(const bf16x8*)((const char*)enc_s + byte);
            }
            #pragma unroll
            for (int nn = 0; nn < 2; ++nn) {
                int n = w * 8 + np * 2 + nn;
                bb[nn] = *(const bf16x8*)(W1T + (size_t)(n * 16 + lc) * 512 + kk * 32 + lg * 8);
            }
            #pragma unroll
            for (int g = 0; g < 4; ++g) {
                acc[g][0] = __builtin_amdgcn_mfma_f32_16x16x32_bf16(a[g], bb[0], acc[g][0], 0, 0, 0);
                acc[g][1] = __builtin_amdgcn_mfma_f32_16x16x32_bf16(a[g], bb[1], acc[g][1], 0, 0, 0);
            }
        }
        #pragma unroll
        for (int nn = 0; nn < 2; ++nn) {
            int u = (w * 8 + np * 2 + nn) * 16 + lc;
            float hd = hdec[b * 512 + u];
            float vv = Vv[u];
            #pragma unroll
            for (int g = 0; g < 4; ++g)
                #pragma unroll
                for (int r = 0; r < 4; ++r)
                    sacc[g][r] += fast_tanh(acc[g][nn][r] + hd) * vv;
        }
    }

    // ---- P3: reduce over u (16 lc lanes), then cross-wave, then softmax (wave 0) ----
    #pragma unroll
    for (int g = 0; g < 4; ++g) {
        #pragma unroll
        for (int r = 0; r < 4; ++r) {
            float v = sacc[g][r];
            v += __shfl_xor(v, 1);
            v += __shfl_xor(v, 2);
            v += __shfl_xor(v, 4);
            v += __shfl_xor(v, 8);
            if (lc == 0) s_sc[w][g * 16 + lg * 4 + r] = v;   // row = g*16 + lg*4 + r
        }
    }
    __syncthreads();
    if (w == 0) {
        float x = s_sc[0][l] + s_sc[1][l] + s_sc[2][l] + s_sc[3][l];
        float mx = x;
        #pragma unroll
        for (int o = 32; o >= 1; o >>= 1) mx = fmaxf(mx, __shfl_xor(mx, o));
        float p = __expf(x - mx);
        float ps = p;
        #pragma unroll
        for (int o = 32; o >= 1; o >>= 1) ps += __shfl_xor(ps, o);
        s_p[l] = p;
        if (l == 0) { s_ml[0] = mx; s_ml[1] = ps; }
    }
    __syncthreads();

    // ---- P4: context partial from LDS. Wave w: rows w*16..+15; lane l: d = l*8..+7. ----
    float c8[8] = {0.f, 0.f, 0.f, 0.f, 0.f, 0.f, 0.f, 0.f};
    #pragma unroll
    for (int rr = 0; rr < 16; ++rr) {
        int row = w * 16 + rr;
        int byte = (row * 1024 + l * 16) ^ ((row & 7) << 4);
        bf16x8 ev = *(const bf16x8*)((const char*)enc_s + byte);
        float p = s_p[row];
        #pragma unroll
        for (int j = 0; j < 8; ++j) c8[j] = fmaf(p, bf2f(ev[j]), c8[j]);
    }
    #pragma unroll
    for (int j = 0; j < 8; ++j) s_ctx[w][l * 8 + j] = c8[j];
    __syncthreads();

    float* part = partials + (size_t)blk * 514;
    int d = tid * 2;
    part[d]     = s_ctx[0][d]     + s_ctx[1][d]     + s_ctx[2][d]     + s_ctx[3][d];
    part[d + 1] = s_ctx[0][d + 1] + s_ctx[1][d + 1] + s_ctx[2][d + 1] + s_ctx[3][d + 1];
    if (tid == 0) { part[512] = s_ml[0]; part[513] = s_ml[1]; }
}

// ---------------- merge: online-softmax merge of 32 chunks per batch ----------------
__global__ void merge_kernel(const float* __restrict__ partials, float* __restrict__ out)
{
    int b = blockIdx.x;     // 64
    int tid = threadIdx.x;  // 256
    const float* pb = partials + (size_t)b * 32 * 514;
    float M = -1e30f;
    #pragma unroll
    for (int i = 0; i < 32; ++i) M = fmaxf(M, pb[i * 514 + 512]);
    float sc[32]; float L = 0.f;
    #pragma unroll
    for (int i = 0; i < 32; ++i) {
        sc[i] = __expf(pb[i * 514 + 512] - M);
        L += pb[i * 514 + 513] * sc[i];
    }
    float inv = 1.0f / L;
    int d = tid * 2;
    #pragma unroll
    for (int t = 0; t < 2; ++t) {
        float acc = 0.f;
        #pragma unroll
        for (int i = 0; i < 32; ++i) acc += pb[i * 514 + d + t] * sc[i];
        out[b * 512 + d + t] = acc * inv;
    }
}

extern "C" void kernel_launch(void* const* d_in, const int* in_sizes, int n_in,
                              void* d_out, int out_size, void* d_ws, size_t ws_size,
                              hipStream_t stream)
{
    const float* enc = (const float*)d_in[0];
    const float* dec = (const float*)d_in[1];
    const float* W1  = (const float*)d_in[2];
    const float* b1  = (const float*)d_in[3];
    const float* W2  = (const float*)d_in[4];
    const float* b2  = (const float*)d_in[5];
    const float* V   = (const float*)d_in[6];
    // d_in[7] = bv: softmax-invariant, dropped.
    float* out = (float*)d_out;

    char* ws = (char*)d_ws;
    float* hdec     = (float*)ws;                                  // 64*512 f32   = 128 KiB
    short* W1T      = (short*)(ws + 64 * 512 * 4);                 // 512*512 bf16 = 512 KiB
    float* partials = (float*)(ws + 64 * 512 * 4 + 512 * 512 * 2); // 2048*514 f32 ~ 4.2 MiB

    hipLaunchKernelGGL(hdec_kernel, dim3(256), dim3(128), 0, stream, dec, W2, b1, b2, hdec);
    hipLaunchKernelGGL(w1t_kernel, dim3(8, 8), dim3(256), 0, stream, W1, W1T);
    hipLaunchKernelGGL(attn_main, dim3(2048), dim3(256), 0, stream, enc, W1T, hdec, V, partials);
    hipLaunchKernelGGL(merge_kernel, dim3(64), dim3(256), 0, stream, partials, out);
}